// Round 3
// baseline (1186.969 us; speedup 1.0000x reference)
//
#include <hip/hip_runtime.h>
#include <hip/hip_bf16.h>

#define NEXP   8
#define MTOK   4096
#define KDIM   2048
#define NINTER 5632
#define NPAIR  8192   // MTOK * TOPK

#define AS3 __attribute__((address_space(3)))
#define AS1 __attribute__((address_space(1)))

typedef __attribute__((ext_vector_type(4))) float f32x4;
typedef __attribute__((ext_vector_type(8))) short s16x8;

#define MEMFENCE asm volatile("" ::: "memory")
#define SB       __builtin_amdgcn_s_barrier()
#define SCHEDB   __builtin_amdgcn_sched_barrier(0)
#define WAITV8   asm volatile("s_waitcnt vmcnt(8)" ::: "memory")
#define WAITV0   asm volatile("s_waitcnt vmcnt(0)" ::: "memory")
#define WAITLG   asm volatile("s_waitcnt lgkmcnt(0)" ::: "memory")

__device__ __forceinline__ short f2bf(float f) {
  union { float f; unsigned u; } v; v.f = f;
  unsigned r = v.u + 0x7FFFu + ((v.u >> 16) & 1u);
  return (short)(r >> 16);
}

__device__ __forceinline__ s16x8 pack8(float4 a, float4 b) {
  s16x8 v;
  v[0] = f2bf(a.x); v[1] = f2bf(a.y); v[2] = f2bf(a.z); v[3] = f2bf(a.w);
  v[4] = f2bf(b.x); v[5] = f2bf(b.y); v[6] = f2bf(b.z); v[7] = f2bf(b.w);
  return v;
}

// ---------------- fp32 -> bf16 one-shot conversion ----------------
__global__ __launch_bounds__(256) void cvt_k(const float* __restrict__ src,
                                             unsigned short* __restrict__ dst, size_t n8) {
  size_t i = (size_t)blockIdx.x * blockDim.x + threadIdx.x;
  size_t stride = (size_t)gridDim.x * blockDim.x;
  for (; i < n8; i += stride) {
    const float4* p = (const float4*)(src + i * 8);
    float4 f0 = p[0], f1 = p[1];
    *(s16x8*)(dst + i * 8) = pack8(f0, f1);
  }
}

// ---------------- routing: deterministic counting sort ----------------
__global__ __launch_bounds__(512) void route_k(const int* __restrict__ ids,
                                               int* __restrict__ off,
                                               int* __restrict__ list) {
  __shared__ int sids[NPAIR];
  __shared__ int scnt[64][8];
  __shared__ int sstart[64][8];
  __shared__ int s_is64;
  int tid = threadIdx.x;
  if (tid == 0) s_is64 = 1;
  __syncthreads();
  for (int i = tid; i < NPAIR / 2; i += 512)
    if (ids[2 * i + 1] != 0) s_is64 = 0;
  __syncthreads();
  int is64 = s_is64;
  for (int i = tid; i < NPAIR; i += 512) {
    int e = is64 ? ids[2 * i] : ids[i];
    if (e < 0) e = 0; if (e > 7) e = 7;
    sids[i] = e;
  }
  if (tid < 64)
    for (int e = 0; e < 8; ++e) scnt[tid][e] = 0;
  __syncthreads();
  if (tid < 64) {
    int b0 = tid * 128;
    for (int i = 0; i < 128; ++i) ++scnt[tid][sids[b0 + i]];
  }
  __syncthreads();
  if (tid == 0) {
    int tot = 0;
    for (int e = 0; e < 8; ++e) {
      off[e] = tot;
      for (int c = 0; c < 64; ++c) { sstart[c][e] = tot; tot += scnt[c][e]; }
    }
    off[8] = tot;
  }
  __syncthreads();
  if (tid < 64) {
    int b0 = tid * 128;
    for (int i = 0; i < 128; ++i) {
      int p = b0 + i;
      int e = sids[p];
      list[sstart[tid][e]++] = p;
    }
  }
}

// ============ GEMM1 (deep pipeline): BM=256, BN=128 gate + 128 up, BK=64, 512 thr ============
// Also converts a slice of w2 fp32->bf16 (overlaps the otherwise-serial cvt_w2 pass).
__global__ __launch_bounds__(512, 2) void gemm1_k8(const float* __restrict__ w2f,
                                                   unsigned short* __restrict__ w2b,
                                                   const unsigned short* __restrict__ a1b,
                                                   const unsigned short* __restrict__ w1b,
                                                   const int* __restrict__ off,
                                                   const int* __restrict__ list,
                                                   unsigned short* __restrict__ act) {
  extern __shared__ __align__(16) char smem[];
  short* sm = (short*)smem;               // lA[2][16384] | lBg[2][8192] | lBu[2][8192] shorts
  int* srow = (int*)(sm + 65536);         // 256 ints

  int tid = threadIdx.x;
  // ---- w2 cvt slice: 11264 blocks x 1024 float8-groups = 11,534,336 exactly ----
  {
    size_t bid = blockIdx.x + (size_t)gridDim.x * (blockIdx.y + (size_t)gridDim.y * blockIdx.z);
    size_t g = bid * 1024 + tid;
    if (g < 11534336u) {
      const float4* s = (const float4*)(w2f + g * 8);
      float4 f0 = s[0], f1 = s[1];
      *(s16x8*)(w2b + g * 8) = pack8(f0, f1);
    }
    g += 512;
    if (g < 11534336u) {
      const float4* s = (const float4*)(w2f + g * 8);
      float4 f0 = s[0], f1 = s[1];
      *(s16x8*)(w2b + g * 8) = pack8(f0, f1);
    }
  }

  int e = blockIdx.z, mt = blockIdx.y, nt = blockIdx.x;
  int base = off[e];
  int cnt  = off[e + 1] - base;
  if (mt * 256 >= cnt) return;

  for (int i = tid; i < 256; i += 512) {
    int r = mt * 256 + i;
    srow[i] = (r < cnt) ? (list[base + r] >> 1) : (list[base + cnt - 1] >> 1);
  }
  __syncthreads();

  int lane = tid & 63, w = tid >> 6;
  int wm = w >> 2, wn = w & 3;
  int lrow = lane & 15, lhi = lane >> 4;
  int l8 = lane >> 3, c8 = lane & 7;

  f32x4 accg[8][2], accu[8][2];
#pragma unroll
  for (int i = 0; i < 8; ++i)
#pragma unroll
    for (int j = 0; j < 2; ++j) { accg[i][j] = (f32x4)(0.f); accu[i][j] = (f32x4)(0.f); }

  // staging sources (pre-swizzled global addresses; LDS dest linear)
  const unsigned short* w1be = w1b + (size_t)e * (2 * NINTER) * KDIM;
  const unsigned short* sA[4];
  const unsigned short* sG[2];
  int aD[4], bD[2];
#pragma unroll
  for (int q = 0; q < 4; ++q) {
    int r = q * 64 + w * 8 + l8;
    sA[q] = a1b + (size_t)srow[r] * KDIM + ((c8 ^ (r & 7)) * 8);
    aD[q] = (q * 64 + w * 8) * 64;
  }
#pragma unroll
  for (int q = 0; q < 2; ++q) {
    int r = q * 64 + w * 8 + l8;
    sG[q] = w1be + (size_t)(nt * 128 + r) * KDIM + ((c8 ^ (r & 7)) * 8);
    bD[q] = (q * 64 + w * 8) * 64;
  }
  const size_t UPOFF = (size_t)NINTER * KDIM;

  auto STAGE = [&](int t, int b) {
    int ko = t * 64;
#pragma unroll
    for (int q = 0; q < 4; ++q)
      __builtin_amdgcn_global_load_lds((const AS1 void*)(sA[q] + ko), (AS3 void*)(sm + b * 16384 + aD[q]), 16, 0, 0);
#pragma unroll
    for (int q = 0; q < 2; ++q) {
      __builtin_amdgcn_global_load_lds((const AS1 void*)(sG[q] + ko), (AS3 void*)(sm + 32768 + b * 8192 + bD[q]), 16, 0, 0);
      __builtin_amdgcn_global_load_lds((const AS1 void*)(sG[q] + UPOFF + ko), (AS3 void*)(sm + 49152 + b * 8192 + bD[q]), 16, 0, 0);
    }
  };

  STAGE(0, 0);
  STAGE(1, 1);
  WAITV8; SCHEDB; MEMFENCE; SB; MEMFENCE; SCHEDB;

  int b = 0;
  for (int t = 0; t < KDIM / 64; ++t) {
    s16x8 aL[4][2], bg[2][2], bu[2][2];
    // A-low + B fragments
#pragma unroll
    for (int i = 0; i < 4; ++i)
#pragma unroll
      for (int kk = 0; kk < 2; ++kk) {
        int r = wm * 128 + i * 16 + lrow, ch = kk * 4 + lhi;
        aL[i][kk] = *(const s16x8*)&sm[b * 16384 + r * 64 + ((ch ^ (r & 7)) * 8)];
      }
#pragma unroll
    for (int j = 0; j < 2; ++j)
#pragma unroll
      for (int kk = 0; kk < 2; ++kk) {
        int r = wn * 32 + j * 16 + lrow, ch = kk * 4 + lhi;
        bg[j][kk] = *(const s16x8*)&sm[32768 + b * 8192 + r * 64 + ((ch ^ (r & 7)) * 8)];
        bu[j][kk] = *(const s16x8*)&sm[49152 + b * 8192 + r * 64 + ((ch ^ (r & 7)) * 8)];
      }
    __builtin_amdgcn_s_setprio(1);
#pragma unroll
    for (int i = 0; i < 4; ++i)
#pragma unroll
      for (int j = 0; j < 2; ++j)
#pragma unroll
        for (int kk = 0; kk < 2; ++kk) {
          accg[i][j] = __builtin_amdgcn_mfma_f32_16x16x32_bf16(aL[i][kk], bg[j][kk], accg[i][j], 0, 0, 0);
          accu[i][j] = __builtin_amdgcn_mfma_f32_16x16x32_bf16(aL[i][kk], bu[j][kk], accu[i][j], 0, 0, 0);
        }
    __builtin_amdgcn_s_setprio(0);
    // A-high (reuse regs)
#pragma unroll
    for (int i = 0; i < 4; ++i)
#pragma unroll
      for (int kk = 0; kk < 2; ++kk) {
        int r = wm * 128 + (i + 4) * 16 + lrow, ch = kk * 4 + lhi;
        aL[i][kk] = *(const s16x8*)&sm[b * 16384 + r * 64 + ((ch ^ (r & 7)) * 8)];
      }
    __builtin_amdgcn_s_setprio(1);
#pragma unroll
    for (int i = 0; i < 4; ++i)
#pragma unroll
      for (int j = 0; j < 2; ++j)
#pragma unroll
        for (int kk = 0; kk < 2; ++kk) {
          accg[i + 4][j] = __builtin_amdgcn_mfma_f32_16x16x32_bf16(aL[i][kk], bg[j][kk], accg[i + 4][j], 0, 0, 0);
          accu[i + 4][j] = __builtin_amdgcn_mfma_f32_16x16x32_bf16(aL[i][kk], bu[j][kk], accu[i + 4][j], 0, 0, 0);
        }
    __builtin_amdgcn_s_setprio(0);

    WAITLG; SCHEDB; MEMFENCE; SB; MEMFENCE; SCHEDB;   // all waves done reading buf b
    if (t + 2 < KDIM / 64) {
      STAGE(t + 2, b);
      WAITV8;                                          // t+1 landed; t+2 stays in flight
    } else {
      WAITV0;
    }
    SCHEDB; MEMFENCE; SB; MEMFENCE; SCHEDB;            // buf b^1 (tile t+1) ready for all
    b ^= 1;
  }

  // epilogue: SwiGLU -> act bf16
#pragma unroll
  for (int i = 0; i < 8; ++i) {
#pragma unroll
    for (int q = 0; q < 4; ++q) {
      int grow = mt * 256 + wm * 128 + i * 16 + lhi * 4 + q;
      if (grow < cnt) {
        size_t rowoff = (size_t)(base + grow) * NINTER;
#pragma unroll
        for (int j = 0; j < 2; ++j) {
          float g = accg[i][j][q], u = accu[i][j][q];
          float a = (g / (1.f + __expf(-g))) * u;
          int col = nt * 128 + wn * 32 + j * 16 + lrow;
          act[rowoff + col] = (unsigned short)f2bf(a);
        }
      }
    }
  }
}

// ============ GEMM2 (deep pipeline): BM=256, BN=256, BK=64, 512 thr ============
__global__ __launch_bounds__(512, 2) void gemm2_k8(const unsigned short* __restrict__ act,
                                                   const unsigned short* __restrict__ w2b,
                                                   const int* __restrict__ off,
                                                   const int* __restrict__ list,
                                                   const float* __restrict__ tw,
                                                   float* __restrict__ out) {
  extern __shared__ __align__(16) char smem[];
  short* sm = (short*)smem;               // lA[2][16384] | lB[2][16384] shorts

  int e = blockIdx.z, mt = blockIdx.y, nt = blockIdx.x;
  int base = off[e];
  int cnt  = off[e + 1] - base;
  if (mt * 256 >= cnt) return;

  int tid = threadIdx.x;
  int lane = tid & 63, w = tid >> 6;
  int wm = w >> 2, wn = w & 3;
  int lrow = lane & 15, lhi = lane >> 4;
  int l8 = lane >> 3, c8 = lane & 7;

  f32x4 acc[8][4];
#pragma unroll
  for (int i = 0; i < 8; ++i)
#pragma unroll
    for (int j = 0; j < 4; ++j) acc[i][j] = (f32x4)(0.f);

  const unsigned short* w2be = w2b + (size_t)e * KDIM * NINTER;
  const unsigned short* sA[4];
  const unsigned short* sB[4];
  int dOf[4];
#pragma unroll
  for (int q = 0; q < 4; ++q) {
    int r = q * 64 + w * 8 + l8;
    int g = mt * 256 + r; if (g >= cnt) g = cnt - 1;
    int swz = (c8 ^ (r & 7)) * 8;
    sA[q] = act + (size_t)(base + g) * NINTER + swz;
    sB[q] = w2be + (size_t)(nt * 256 + r) * NINTER + swz;
    dOf[q] = (q * 64 + w * 8) * 64;
  }

  auto STAGE = [&](int t, int b) {
    int ko = t * 64;
#pragma unroll
    for (int q = 0; q < 4; ++q)
      __builtin_amdgcn_global_load_lds((const AS1 void*)(sA[q] + ko), (AS3 void*)(sm + b * 16384 + dOf[q]), 16, 0, 0);
#pragma unroll
    for (int q = 0; q < 4; ++q)
      __builtin_amdgcn_global_load_lds((const AS1 void*)(sB[q] + ko), (AS3 void*)(sm + 32768 + b * 16384 + dOf[q]), 16, 0, 0);
  };

  STAGE(0, 0);
  STAGE(1, 1);
  WAITV8; SCHEDB; MEMFENCE; SB; MEMFENCE; SCHEDB;

  int b = 0;
  for (int t = 0; t < NINTER / 64; ++t) {
    s16x8 aL[4][2], bb[4][2];
#pragma unroll
    for (int i = 0; i < 4; ++i)
#pragma unroll
      for (int kk = 0; kk < 2; ++kk) {
        int r = wm * 128 + i * 16 + lrow, ch = kk * 4 + lhi;
        aL[i][kk] = *(const s16x8*)&sm[b * 16384 + r * 64 + ((ch ^ (r & 7)) * 8)];
      }
#pragma unroll
    for (int j = 0; j < 4; ++j)
#pragma unroll
      for (int kk = 0; kk < 2; ++kk) {
        int r = wn * 64 + j * 16 + lrow, ch = kk * 4 + lhi;
        bb[j][kk] = *(const s16x8*)&sm[32768 + b * 16384 + r * 64 + ((ch ^ (r & 7)) * 8)];
      }
    __builtin_amdgcn_s_setprio(1);
#pragma unroll
    for (int i = 0; i < 4; ++i)
#pragma unroll
      for (int j = 0; j < 4; ++j)
#pragma unroll
        for (int kk = 0; kk < 2; ++kk)
          acc[i][j] = __builtin_amdgcn_mfma_f32_16x16x32_bf16(aL[i][kk], bb[j][kk], acc[i][j], 0, 0, 0);
    __builtin_amdgcn_s_setprio(0);
#pragma unroll
    for (int i = 0; i < 4; ++i)
#pragma unroll
      for (int kk = 0; kk < 2; ++kk) {
        int r = wm * 128 + (i + 4) * 16 + lrow, ch = kk * 4 + lhi;
        aL[i][kk] = *(const s16x8*)&sm[b * 16384 + r * 64 + ((ch ^ (r & 7)) * 8)];
      }
    __builtin_amdgcn_s_setprio(1);
#pragma unroll
    for (int i = 0; i < 4; ++i)
#pragma unroll
      for (int j = 0; j < 4; ++j)
#pragma unroll
        for (int kk = 0; kk < 2; ++kk)
          acc[i + 4][j] = __builtin_amdgcn_mfma_f32_16x16x32_bf16(aL[i][kk], bb[j][kk], acc[i + 4][j], 0, 0, 0);
    __builtin_amdgcn_s_setprio(0);

    WAITLG; SCHEDB; MEMFENCE; SB; MEMFENCE; SCHEDB;
    if (t + 2 < NINTER / 64) {
      STAGE(t + 2, b);
      WAITV8;
    } else {
      WAITV0;
    }
    SCHEDB; MEMFENCE; SB; MEMFENCE; SCHEDB;
    b ^= 1;
  }

  // epilogue: weighted atomic scatter
#pragma unroll
  for (int i = 0; i < 8; ++i) {
#pragma unroll
    for (int q = 0; q < 4; ++q) {
      int grow = mt * 256 + wm * 128 + i * 16 + lhi * 4 + q;
      if (grow < cnt) {
        int p = list[base + grow];
        int m = p >> 1;
        float wgt = tw[p];
#pragma unroll
        for (int j = 0; j < 4; ++j) {
          int col = nt * 256 + wn * 64 + j * 16 + lrow;
          atomicAdd(&out[(size_t)m * KDIM + col], wgt * acc[i][j][q]);
        }
      }
    }
  }
}

// ============ fallback (fp32 inputs, 128^2, from round 1/2 — used only if ws too small) ============
__global__ __launch_bounds__(256, 2) void gemm1_fb(const float* __restrict__ a1,
                                                   const float* __restrict__ w1,
                                                   const int* __restrict__ off,
                                                   const int* __restrict__ list,
                                                   unsigned short* __restrict__ act) {
  int e = blockIdx.z, mt = blockIdx.y, nt = blockIdx.x;
  int base = off[e];
  int cnt  = off[e + 1] - base;
  if (mt * 128 >= cnt) return;
  __shared__ __align__(16) short lA[128 * 64];
  __shared__ __align__(16) short lBg[128 * 64];
  __shared__ __align__(16) short lBu[128 * 64];
  __shared__ int srow[128];
  int tid = threadIdx.x;
  if (tid < 128) {
    int r = mt * 128 + tid;
    srow[tid] = (r < cnt) ? (list[base + r] >> 1) : 0;
  }
  __syncthreads();
  int lane = tid & 63, wave = tid >> 6;
  int wm = wave >> 1, wn = wave & 1;
  int lrow = lane & 15, lhi = lane >> 4;
  f32x4 accg[4][4], accu[4][4];
#pragma unroll
  for (int i = 0; i < 4; ++i)
#pragma unroll
    for (int j = 0; j < 4; ++j) { accg[i][j] = (f32x4)(0.f); accu[i][j] = (f32x4)(0.f); }
  const float* w1e = w1 + (size_t)e * (2 * NINTER) * KDIM;
  int n0 = nt * 128;
  for (int k0 = 0; k0 < KDIM; k0 += 64) {
#pragma unroll
    for (int c4 = 0; c4 < 4; ++c4) {
      int cid = c4 * 256 + tid;
      int row = cid >> 3, k8 = cid & 7;
      const float* s = a1 + (size_t)srow[row] * KDIM + k0 + k8 * 8;
      float4 f0 = *(const float4*)s;
      float4 f1 = *(const float4*)(s + 4);
      *(s16x8*)&lA[row * 64 + ((k8 ^ (row & 7)) * 8)] = pack8(f0, f1);
    }
#pragma unroll
    for (int c4 = 0; c4 < 4; ++c4) {
      int cid = c4 * 256 + tid;
      int row = cid >> 3, k8 = cid & 7;
      const float* sg = w1e + (size_t)(n0 + row) * KDIM + k0 + k8 * 8;
      const float* su = w1e + (size_t)(NINTER + n0 + row) * KDIM + k0 + k8 * 8;
      float4 g0 = *(const float4*)sg;
      float4 g1 = *(const float4*)(sg + 4);
      float4 u0 = *(const float4*)su;
      float4 u1 = *(const float4*)(su + 4);
      int o = row * 64 + ((k8 ^ (row & 7)) * 8);
      *(s16x8*)&lBg[o] = pack8(g0, g1);
      *(s16x8*)&lBu[o] = pack8(u0, u1);
    }
    __syncthreads();
#pragma unroll
    for (int kk = 0; kk < 2; ++kk) {
      s16x8 af[4], bg[4], bu[4];
      int chunk = kk * 4 + lhi;
#pragma unroll
      for (int i = 0; i < 4; ++i) {
        int r = wm * 64 + i * 16 + lrow;
        af[i] = *(const s16x8*)&lA[r * 64 + ((chunk ^ (r & 7)) * 8)];
      }
#pragma unroll
      for (int j = 0; j < 4; ++j) {
        int r = wn * 64 + j * 16 + lrow;
        int o = r * 64 + ((chunk ^ (r & 7)) * 8);
        bg[j] = *(const s16x8*)&lBg[o];
        bu[j] = *(const s16x8*)&lBu[o];
      }
#pragma unroll
      for (int i = 0; i < 4; ++i)
#pragma unroll
        for (int j = 0; j < 4; ++j) {
          accg[i][j] = __builtin_amdgcn_mfma_f32_16x16x32_bf16(af[i], bg[j], accg[i][j], 0, 0, 0);
          accu[i][j] = __builtin_amdgcn_mfma_f32_16x16x32_bf16(af[i], bu[j], accu[i][j], 0, 0, 0);
        }
    }
    __syncthreads();
  }
#pragma unroll
  for (int i = 0; i < 4; ++i) {
#pragma unroll
    for (int q = 0; q < 4; ++q) {
      int r = wm * 64 + i * 16 + lhi * 4 + q;
      int grow = mt * 128 + r;
      if (grow < cnt) {
        size_t rowoff = (size_t)(base + grow) * NINTER;
#pragma unroll
        for (int j = 0; j < 4; ++j) {
          float g = accg[i][j][q], u = accu[i][j][q];
          float a = (g / (1.f + __expf(-g))) * u;
          int col = n0 + wn * 64 + j * 16 + lrow;
          act[rowoff + col] = (unsigned short)f2bf(a);
        }
      }
    }
  }
}

__global__ __launch_bounds__(256, 2) void gemm2_fb(const unsigned short* __restrict__ act,
                                                   const float* __restrict__ w2,
                                                   const int* __restrict__ off,
                                                   const int* __restrict__ list,
                                                   const float* __restrict__ tw,
                                                   float* __restrict__ out) {
  int e = blockIdx.z, mt = blockIdx.y, nt = blockIdx.x;
  int base = off[e];
  int cnt  = off[e + 1] - base;
  if (mt * 128 >= cnt) return;
  __shared__ __align__(16) short lA[128 * 64];
  __shared__ __align__(16) short lB[128 * 64];
  int tid = threadIdx.x;
  int lane = tid & 63, wave = tid >> 6;
  int wm = wave >> 1, wn = wave & 1;
  int lrow = lane & 15, lhi = lane >> 4;
  f32x4 acc[4][4];
#pragma unroll
  for (int i = 0; i < 4; ++i)
#pragma unroll
    for (int j = 0; j < 4; ++j) acc[i][j] = (f32x4)(0.f);
  const float* w2e = w2 + (size_t)e * KDIM * NINTER;
  for (int k0 = 0; k0 < NINTER; k0 += 64) {
#pragma unroll
    for (int c4 = 0; c4 < 4; ++c4) {
      int cid = c4 * 256 + tid;
      int row = cid >> 3, k8 = cid & 7;
      int grow = mt * 128 + row;
      if (grow >= cnt) grow = cnt - 1;
      s16x8 v = *(const s16x8*)(act + (size_t)(base + grow) * NINTER + k0 + k8 * 8);
      *(s16x8*)&lA[row * 64 + ((k8 ^ (row & 7)) * 8)] = v;
    }
#pragma unroll
    for (int c4 = 0; c4 < 4; ++c4) {
      int cid = c4 * 256 + tid;
      int row = cid >> 3, k8 = cid & 7;
      const float* s = w2e + (size_t)(nt * 128 + row) * NINTER + k0 + k8 * 8;
      float4 f0 = *(const float4*)s;
      float4 f1 = *(const float4*)(s + 4);
      *(s16x8*)&lB[row * 64 + ((k8 ^ (row & 7)) * 8)] = pack8(f0, f1);
    }
    __syncthreads();
#pragma unroll
    for (int kk = 0; kk < 2; ++kk) {
      s16x8 af[4], bf[4];
      int chunk = kk * 4 + lhi;
#pragma unroll
      for (int i = 0; i < 4; ++i) {
        int r = wm * 64 + i * 16 + lrow;
        af[i] = *(const s16x8*)&lA[r * 64 + ((chunk ^ (r & 7)) * 8)];
      }
#pragma unroll
      for (int j = 0; j < 4; ++j) {
        int r = wn * 64 + j * 16 + lrow;
        bf[j] = *(const s16x8*)&lB[r * 64 + ((chunk ^ (r & 7)) * 8)];
      }
#pragma unroll
      for (int i = 0; i < 4; ++i)
#pragma unroll
        for (int j = 0; j < 4; ++j)
          acc[i][j] = __builtin_amdgcn_mfma_f32_16x16x32_bf16(af[i], bf[j], acc[i][j], 0, 0, 0);
    }
    __syncthreads();
  }
#pragma unroll
  for (int i = 0; i < 4; ++i) {
#pragma unroll
    for (int q = 0; q < 4; ++q) {
      int r = wm * 64 + i * 16 + lhi * 4 + q;
      int grow = mt * 128 + r;
      if (grow < cnt) {
        int p = list[base + grow];
        int m = p >> 1;
        float wgt = tw[p];
#pragma unroll
        for (int j = 0; j < 4; ++j) {
          int col = nt * 128 + wn * 64 + j * 16 + lrow;
          atomicAdd(&out[(size_t)m * KDIM + col], wgt * acc[i][j][q]);
        }
      }
    }
  }
}

extern "C" void kernel_launch(void* const* d_in, const int* in_sizes, int n_in,
                              void* d_out, int out_size, void* d_ws, size_t ws_size,
                              hipStream_t stream) {
  const float* a1 = (const float*)d_in[0];
  const float* w1 = (const float*)d_in[1];
  const float* w2 = (const float*)d_in[2];
  const float* tw = (const float*)d_in[3];
  const int*   ids = (const int*)d_in[4];
  float* out = (float*)d_out;

  int* off  = (int*)d_ws;
  int* list = off + 16;
  unsigned short* act = (unsigned short*)((char*)d_ws + 65536);
  size_t actB = (size_t)NPAIR * NINTER * 2;
  unsigned short* a1b = (unsigned short*)((char*)act + actB);
  size_t a1B = (size_t)MTOK * KDIM * 2;
  unsigned short* w1b = (unsigned short*)((char*)a1b + a1B);
  size_t w1B = (size_t)NEXP * 2 * NINTER * KDIM * 2;
  unsigned short* w2b = (unsigned short*)((char*)w1b + w1B);
  size_t w2B = (size_t)NEXP * KDIM * NINTER * 2;
  size_t need = 65536 + actB + a1B + w1B + w2B;

  hipMemsetAsync(d_out, 0, (size_t)MTOK * KDIM * sizeof(float), stream);
  route_k<<<1, 512, 0, stream>>>(ids, off, list);

  if (ws_size >= need) {
    hipFuncSetAttribute((const void*)gemm1_k8, hipFuncAttributeMaxDynamicSharedMemorySize, 132096);
    hipFuncSetAttribute((const void*)gemm2_k8, hipFuncAttributeMaxDynamicSharedMemorySize, 131072);
    cvt_k<<<2048, 256, 0, stream>>>(a1, a1b, (size_t)MTOK * KDIM / 8);
    cvt_k<<<2048, 256, 0, stream>>>(w1, w1b, (size_t)NEXP * 2 * NINTER * KDIM / 8);
    gemm1_k8<<<dim3(NINTER / 128, 32, NEXP), 512, 132096, stream>>>(w2, w2b, a1b, w1b, off, list, act);
    gemm2_k8<<<dim3(KDIM / 256, 32, NEXP), 512, 131072, stream>>>(act, w2b, off, list, tw, out);
  } else {
    gemm1_fb<<<dim3(NINTER / 128, 64, NEXP), 256, 0, stream>>>(a1, w1, off, list, act);
    gemm2_fb<<<dim3(KDIM / 128, 64, NEXP), 256, 0, stream>>>(act, w2, off, list, tw, out);
  }
}